// Round 1
// baseline (5845.818 us; speedup 1.0000x reference)
//
#include <hip/hip_runtime.h>
#include <math.h>

// ---------------------------------------------------------------------------
// Encoder: GCN(2 layers) + per-graph mean pool + FF MLP on pooled rows + sigmoid
// N=100000 nodes, E=1600000 edges, D=128, G=256 graphs (graph_id sorted)
// ---------------------------------------------------------------------------

#define D 128
#define G 256

// ---- Tiled fp32 GEMM: Y[nrows x 128] = transform(X) @ W (W row-major k*128+c)
// transform: optional (X + bias) then relu, fused on load.
template<bool BIAS_RELU>
__global__ __launch_bounds__(256, 2)
void gemm128(const float* __restrict__ X, const float* __restrict__ W,
             const float* __restrict__ bias, float* __restrict__ Y, int nrows) {
    __shared__ float Ws[64][128];   // 32 KB (k-chunked)
    __shared__ float Xs[32][129];   // 16.5 KB (pad to avoid conflicts)
    const int tid = threadIdx.x;
    const int r0 = blockIdx.x * 32;

    // stage X tile (with fused bias+relu for layer-2 input)
    for (int i = tid; i < 32 * 128; i += 256) {
        int r = i >> 7, k = i & 127;
        int gr = r0 + r;
        float v = (gr < nrows) ? X[(size_t)gr * D + k] : 0.f;
        if (BIAS_RELU) v = fmaxf(v + bias[k], 0.f);
        Xs[r][k] = v;
    }

    const int c0 = (tid & 63) * 2;   // column pair
    const int rb = (tid >> 6) * 8;   // 8 rows per thread
    float2 acc[8];
#pragma unroll
    for (int i = 0; i < 8; i++) acc[i] = make_float2(0.f, 0.f);

    for (int kb = 0; kb < 128; kb += 64) {
        __syncthreads();  // Xs ready (1st iter) / Ws no longer in use (2nd iter)
        for (int i = tid; i < 64 * 128; i += 256) {
            int k = i >> 7, c = i & 127;
            Ws[k][c] = W[(size_t)(kb + k) * D + c];
        }
        __syncthreads();
#pragma unroll 8
        for (int k = 0; k < 64; k++) {
            float w0 = Ws[k][c0], w1 = Ws[k][c0 + 1];
#pragma unroll
            for (int i = 0; i < 8; i++) {
                float xv = Xs[rb + i][kb + k];   // broadcast within wave
                acc[i].x = fmaf(xv, w0, acc[i].x);
                acc[i].y = fmaf(xv, w1, acc[i].y);
            }
        }
    }
#pragma unroll
    for (int i = 0; i < 8; i++) {
        int gr = r0 + rb + i;
        if (gr < nrows)
            *(float2*)(Y + (size_t)gr * D + c0) = acc[i];
    }
}

// ---- Edge-parallel SpMM: out[dst] += w * X[src], atomics. One thread = 4 dims.
__global__ __launch_bounds__(256)
void spmm_atomic(const float* __restrict__ X, const float* __restrict__ ew,
                 const int* __restrict__ src, const int* __restrict__ dst,
                 float* __restrict__ out, int nedges) {
    unsigned idx = blockIdx.x * 256u + threadIdx.x;
    unsigned e = idx >> 5;
    if (e >= (unsigned)nedges) return;
    int d0 = (idx & 31) * 4;
    int s = src[e], t = dst[e];
    float w = ew[e];
    const float4 xv = *(const float4*)(X + (size_t)s * D + d0);
    float* o = out + (size_t)t * D + d0;
    atomicAdd(o + 0, w * xv.x);
    atomicAdd(o + 1, w * xv.y);
    atomicAdd(o + 2, w * xv.z);
    atomicAdd(o + 3, w * xv.w);
}

// ---- Per-graph histogram of node counts
__global__ void hist_kernel(const int* __restrict__ gid, int* __restrict__ cnt, int n) {
    int i = blockIdx.x * blockDim.x + threadIdx.x;
    if (i < n) atomicAdd(&cnt[gid[i]], 1);
}

// ---- Exclusive scan over 256 bins -> ptr[257]
__global__ void scan_kernel(const int* __restrict__ cnt, int* __restrict__ ptr) {
    __shared__ int s[G];
    int t = threadIdx.x;
    s[t] = cnt[t];
    __syncthreads();
    for (int off = 1; off < G; off <<= 1) {
        int x = (t >= off) ? s[t - off] : 0;
        __syncthreads();
        s[t] += x;
        __syncthreads();
    }
    ptr[t + 1] = s[t];
    if (t == 0) ptr[0] = 0;
}

// ---- Per-graph mean pool (graph_id sorted => contiguous row ranges) + b2
__global__ __launch_bounds__(128)
void pool_kernel(const float* __restrict__ S, const int* __restrict__ ptr,
                 const float* __restrict__ b2, float* __restrict__ pooled) {
    int g = blockIdx.x, d = threadIdx.x;
    int beg = ptr[g], end = ptr[g + 1];
    float acc = 0.f;
    for (int n = beg; n < end; n++) acc += S[(size_t)n * D + d];
    int cnt = end - beg;
    pooled[g * D + d] = (cnt > 0) ? (acc / (float)cnt + b2[d]) : 0.f;
}

// ---- FF MLP on 256 pooled rows + shortcut + sigmoid
__global__ __launch_bounds__(128)
void ff_kernel(const float* __restrict__ pooled,
               const float* __restrict__ W1, const float* __restrict__ b1,
               const float* __restrict__ W2, const float* __restrict__ b2,
               const float* __restrict__ W3, const float* __restrict__ b3,
               const float* __restrict__ Wsc, const float* __restrict__ bsc,
               float* __restrict__ ffout) {
    __shared__ float hx[D], za[D], zb[D];
    int g = blockIdx.x, d = threadIdx.x;
    hx[d] = pooled[g * D + d];
    __syncthreads();
    float s = b1[d];
    for (int k = 0; k < D; k++) s = fmaf(hx[k], W1[k * D + d], s);
    za[d] = fmaxf(s, 0.f);
    __syncthreads();
    s = b2[d];
    for (int k = 0; k < D; k++) s = fmaf(za[k], W2[k * D + d], s);
    zb[d] = fmaxf(s, 0.f);
    __syncthreads();
    s = b3[d];
    for (int k = 0; k < D; k++) s = fmaf(zb[k], W3[k * D + d], s);
    float z3 = fmaxf(s, 0.f);
    float sc = bsc[d];
    for (int k = 0; k < D; k++) sc = fmaf(hx[k], Wsc[k * D + d], sc);
    float v = z3 + sc;
    ffout[g * D + d] = 1.f / (1.f + expf(-v));
}

// ---- Scatter pooled FF result back to all nodes
__global__ __launch_bounds__(256)
void scatter_kernel(const float* __restrict__ ffout, const int* __restrict__ gid,
                    float* __restrict__ out, int n) {
    unsigned idx = blockIdx.x * 256u + threadIdx.x;
    unsigned node = idx >> 5;
    if (node >= (unsigned)n) return;
    int d0 = (idx & 31) * 4;
    int g = gid[node];
    *(float4*)(out + (size_t)node * D + d0) = *(const float4*)(ffout + g * D + d0);
}

extern "C" void kernel_launch(void* const* d_in, const int* in_sizes, int n_in,
                              void* d_out, int out_size, void* d_ws, size_t ws_size,
                              hipStream_t stream) {
    const float* feat = (const float*)d_in[0];
    const float* ew   = (const float*)d_in[1];
    const float* W1   = (const float*)d_in[2];
    const float* b1   = (const float*)d_in[3];
    const float* W2   = (const float*)d_in[4];
    const float* b2   = (const float*)d_in[5];
    const float* ffW1 = (const float*)d_in[6];
    const float* ffb1 = (const float*)d_in[7];
    const float* ffW2 = (const float*)d_in[8];
    const float* ffb2 = (const float*)d_in[9];
    const float* ffW3 = (const float*)d_in[10];
    const float* ffb3 = (const float*)d_in[11];
    const float* ffWs = (const float*)d_in[12];
    const float* ffbs = (const float*)d_in[13];
    const int* esrc = (const int*)d_in[14];
    const int* edst = (const int*)d_in[15];
    const int* gid  = (const int*)d_in[16];

    const int N = in_sizes[0] / D;
    const int E = in_sizes[1];
    float* out = (float*)d_out;

    // workspace layout
    char* ws = (char*)d_ws;
    float* A = (float*)ws;                                 // N*D floats (dense GEMM out)
    size_t offA = (size_t)N * D * sizeof(float);
    float* pooled = (float*)(ws + offA);                   // G*D
    float* ffo = pooled + G * D;                           // G*D
    int* cnt = (int*)(ffo + G * D);                        // G
    int* ptr = cnt + G;                                    // G+1

    float* S = out;  // reuse output buffer as SpMM accumulator

    const dim3 blk(256);
    const int gemmGrid = (N + 31) / 32;
    const int spmmGrid = (int)(((size_t)E * 32 + 255) / 256);

    // 1. A = feat @ W1
    gemm128<false><<<gemmGrid, blk, 0, stream>>>(feat, W1, nullptr, A, N);
    // 2. S = spmm(A)
    hipMemsetAsync(S, 0, (size_t)N * D * sizeof(float), stream);
    spmm_atomic<<<spmmGrid, blk, 0, stream>>>(A, ew, esrc, edst, S, E);
    // 3. A = relu(S + b1) @ W2
    gemm128<true><<<gemmGrid, blk, 0, stream>>>(S, W2, b1, A, N);
    // 4. S = spmm(A)
    hipMemsetAsync(S, 0, (size_t)N * D * sizeof(float), stream);
    spmm_atomic<<<spmmGrid, blk, 0, stream>>>(A, ew, esrc, edst, S, E);
    // 5. graph histogram + scan
    hipMemsetAsync(cnt, 0, G * sizeof(int), stream);
    hist_kernel<<<(N + 255) / 256, blk, 0, stream>>>(gid, cnt, N);
    scan_kernel<<<1, G, 0, stream>>>(cnt, ptr);
    // 6. pooled[g] = mean(S rows of g) + b2
    pool_kernel<<<G, 128, 0, stream>>>(S, ptr, b2, pooled);
    // 7. FF MLP + sigmoid on pooled rows only
    ff_kernel<<<G, 128, 0, stream>>>(pooled, ffW1, ffb1, ffW2, ffb2,
                                     ffW3, ffb3, ffWs, ffbs, ffo);
    // 8. out[n] = ffo[graph_id[n]]
    scatter_kernel<<<(int)(((size_t)N * 32 + 255) / 256), blk, 0, stream>>>(ffo, gid, out, N);
}

// Round 2
// 899.955 us; speedup vs baseline: 6.4957x; 6.4957x over previous
//
#include <hip/hip_runtime.h>
#include <math.h>

// ---------------------------------------------------------------------------
// Encoder: GCN(2 layers) + per-graph mean pool + FF MLP on pooled rows + sigmoid
// N=100000 nodes, E=1600000 edges, D=128, G=256 graphs (graph_id sorted)
// Round 2: replace edge-parallel atomic SpMM (was 2x2675us, atomic-bound)
// with on-device counting-sort -> CSR-by-dst + row-parallel gather SpMM.
// ---------------------------------------------------------------------------

#define D 128
#define G 256
#define SCAN_CHUNK 1024

// ---- Tiled fp32 GEMM: Y[nrows x 128] = transform(X) @ W (W row-major k*128+c)
template<bool BIAS_RELU>
__global__ __launch_bounds__(256, 2)
void gemm128(const float* __restrict__ X, const float* __restrict__ W,
             const float* __restrict__ bias, float* __restrict__ Y, int nrows) {
    __shared__ float Ws[64][128];
    __shared__ float Xs[32][129];
    const int tid = threadIdx.x;
    const int r0 = blockIdx.x * 32;

    for (int i = tid; i < 32 * 128; i += 256) {
        int r = i >> 7, k = i & 127;
        int gr = r0 + r;
        float v = (gr < nrows) ? X[(size_t)gr * D + k] : 0.f;
        if (BIAS_RELU) v = fmaxf(v + bias[k], 0.f);
        Xs[r][k] = v;
    }

    const int c0 = (tid & 63) * 2;
    const int rb = (tid >> 6) * 8;
    float2 acc[8];
#pragma unroll
    for (int i = 0; i < 8; i++) acc[i] = make_float2(0.f, 0.f);

    for (int kb = 0; kb < 128; kb += 64) {
        __syncthreads();
        for (int i = tid; i < 64 * 128; i += 256) {
            int k = i >> 7, c = i & 127;
            Ws[k][c] = W[(size_t)(kb + k) * D + c];
        }
        __syncthreads();
#pragma unroll 8
        for (int k = 0; k < 64; k++) {
            float w0 = Ws[k][c0], w1 = Ws[k][c0 + 1];
#pragma unroll
            for (int i = 0; i < 8; i++) {
                float xv = Xs[rb + i][kb + k];
                acc[i].x = fmaf(xv, w0, acc[i].x);
                acc[i].y = fmaf(xv, w1, acc[i].y);
            }
        }
    }
#pragma unroll
    for (int i = 0; i < 8; i++) {
        int gr = r0 + rb + i;
        if (gr < nrows)
            *(float2*)(Y + (size_t)gr * D + c0) = acc[i];
    }
}

// ======================= CSR build (counting sort by dst) ===================

__global__ __launch_bounds__(256)
void count_dst(const int* __restrict__ dst, int* __restrict__ cnt, int ne) {
    int e = blockIdx.x * 256 + threadIdx.x;
    if (e < ne) atomicAdd(&cnt[dst[e]], 1);
}

// block inclusive scan over chunks of 1024 (4 elems/thread, 256 threads)
__global__ __launch_bounds__(256)
void scan_a(const int* __restrict__ cnt, int* __restrict__ incl,
            int* __restrict__ bsum, int n) {
    __shared__ int s[256];
    int b = blockIdx.x, t = threadIdx.x;
    int base = b * SCAN_CHUNK + t * 4;
    int v[4];
    int sum = 0;
#pragma unroll
    for (int i = 0; i < 4; i++) {
        int idx = base + i;
        v[i] = (idx < n) ? cnt[idx] : 0;
        sum += v[i];
    }
    s[t] = sum;
    __syncthreads();
    for (int off = 1; off < 256; off <<= 1) {
        int x = (t >= off) ? s[t - off] : 0;
        __syncthreads();
        s[t] += x;
        __syncthreads();
    }
    int run = s[t] - sum;
#pragma unroll
    for (int i = 0; i < 4; i++) {
        run += v[i];
        int idx = base + i;
        if (idx < n) incl[idx] = run;
    }
    if (t == 255) bsum[b] = s[255];
}

__global__ void scan_b(const int* __restrict__ bsum, int* __restrict__ boff, int nb) {
    __shared__ int s[256];
    int t = threadIdx.x;
    int v = (t < nb) ? bsum[t] : 0;
    s[t] = v;
    __syncthreads();
    for (int off = 1; off < 256; off <<= 1) {
        int x = (t >= off) ? s[t - off] : 0;
        __syncthreads();
        s[t] += x;
        __syncthreads();
    }
    boff[t] = s[t] - v;
}

__global__ __launch_bounds__(256)
void scan_c(const int* __restrict__ cnt, const int* __restrict__ incl,
            const int* __restrict__ boff, int* __restrict__ rp,
            int* __restrict__ cursor, int n) {
    int i = blockIdx.x * 256 + threadIdx.x;
    if (i >= n) return;
    int tot = incl[i] + boff[i / SCAN_CHUNK];
    rp[i + 1] = tot;
    cursor[i] = tot - cnt[i];
    if (i == 0) rp[0] = 0;
}

__global__ __launch_bounds__(256)
void fill_csr(const int* __restrict__ src, const int* __restrict__ dst,
              const float* __restrict__ ew, int* __restrict__ cursor,
              int2* __restrict__ ep, int ne) {
    int e = blockIdx.x * 256 + threadIdx.x;
    if (e >= ne) return;
    int t = dst[e];
    int pos = atomicAdd(&cursor[t], 1);
    ep[pos] = make_int2(src[e], __float_as_int(ew[e]));
}

// ---- Row-parallel gather SpMM: one wave per row, lane owns 2 dims
__global__ __launch_bounds__(256)
void spmm_csr(const float* __restrict__ X, const int2* __restrict__ ep,
              const int* __restrict__ rp, float* __restrict__ out, int nrows) {
    int row = blockIdx.x * 4 + (threadIdx.x >> 6);
    if (row >= nrows) return;
    int d0 = (threadIdx.x & 63) * 2;
    int beg = rp[row], end = rp[row + 1];
    float2 a0 = make_float2(0.f, 0.f), a1 = make_float2(0.f, 0.f);
    int j = beg;
    for (; j + 1 < end; j += 2) {
        int2 e0 = ep[j], e1 = ep[j + 1];
        float w0 = __int_as_float(e0.y), w1 = __int_as_float(e1.y);
        float2 x0 = *(const float2*)(X + (size_t)e0.x * D + d0);
        float2 x1 = *(const float2*)(X + (size_t)e1.x * D + d0);
        a0.x = fmaf(w0, x0.x, a0.x);
        a0.y = fmaf(w0, x0.y, a0.y);
        a1.x = fmaf(w1, x1.x, a1.x);
        a1.y = fmaf(w1, x1.y, a1.y);
    }
    if (j < end) {
        int2 e0 = ep[j];
        float w0 = __int_as_float(e0.y);
        float2 x0 = *(const float2*)(X + (size_t)e0.x * D + d0);
        a0.x = fmaf(w0, x0.x, a0.x);
        a0.y = fmaf(w0, x0.y, a0.y);
    }
    a0.x += a1.x;
    a0.y += a1.y;
    *(float2*)(out + (size_t)row * D + d0) = a0;
}

// ======================= graph pooling + FF =================================

__global__ void hist_kernel(const int* __restrict__ gid, int* __restrict__ cnt, int n) {
    int i = blockIdx.x * blockDim.x + threadIdx.x;
    if (i < n) atomicAdd(&cnt[gid[i]], 1);
}

__global__ void scan_kernel(const int* __restrict__ cnt, int* __restrict__ ptr) {
    __shared__ int s[G];
    int t = threadIdx.x;
    s[t] = cnt[t];
    __syncthreads();
    for (int off = 1; off < G; off <<= 1) {
        int x = (t >= off) ? s[t - off] : 0;
        __syncthreads();
        s[t] += x;
        __syncthreads();
    }
    ptr[t + 1] = s[t];
    if (t == 0) ptr[0] = 0;
}

__global__ __launch_bounds__(128)
void pool_kernel(const float* __restrict__ S, const int* __restrict__ ptr,
                 const float* __restrict__ b2, float* __restrict__ pooled) {
    int g = blockIdx.x, d = threadIdx.x;
    int beg = ptr[g], end = ptr[g + 1];
    float acc = 0.f;
    for (int n = beg; n < end; n++) acc += S[(size_t)n * D + d];
    int cnt = end - beg;
    pooled[g * D + d] = (cnt > 0) ? (acc / (float)cnt + b2[d]) : 0.f;
}

__global__ __launch_bounds__(128)
void ff_kernel(const float* __restrict__ pooled,
               const float* __restrict__ W1, const float* __restrict__ b1,
               const float* __restrict__ W2, const float* __restrict__ b2,
               const float* __restrict__ W3, const float* __restrict__ b3,
               const float* __restrict__ Wsc, const float* __restrict__ bsc,
               float* __restrict__ ffout) {
    __shared__ float hx[D], za[D], zb[D];
    int g = blockIdx.x, d = threadIdx.x;
    hx[d] = pooled[g * D + d];
    __syncthreads();
    float s = b1[d];
    for (int k = 0; k < D; k++) s = fmaf(hx[k], W1[k * D + d], s);
    za[d] = fmaxf(s, 0.f);
    __syncthreads();
    s = b2[d];
    for (int k = 0; k < D; k++) s = fmaf(za[k], W2[k * D + d], s);
    zb[d] = fmaxf(s, 0.f);
    __syncthreads();
    s = b3[d];
    for (int k = 0; k < D; k++) s = fmaf(zb[k], W3[k * D + d], s);
    float z3 = fmaxf(s, 0.f);
    float sc = bsc[d];
    for (int k = 0; k < D; k++) sc = fmaf(hx[k], Wsc[k * D + d], sc);
    float v = z3 + sc;
    ffout[g * D + d] = 1.f / (1.f + expf(-v));
}

__global__ __launch_bounds__(256)
void scatter_kernel(const float* __restrict__ ffout, const int* __restrict__ gid,
                    float* __restrict__ out, int n) {
    unsigned idx = blockIdx.x * 256u + threadIdx.x;
    unsigned node = idx >> 5;
    if (node >= (unsigned)n) return;
    int d0 = (idx & 31) * 4;
    int g = gid[node];
    *(float4*)(out + (size_t)node * D + d0) = *(const float4*)(ffout + g * D + d0);
}

extern "C" void kernel_launch(void* const* d_in, const int* in_sizes, int n_in,
                              void* d_out, int out_size, void* d_ws, size_t ws_size,
                              hipStream_t stream) {
    const float* feat = (const float*)d_in[0];
    const float* ew   = (const float*)d_in[1];
    const float* W1   = (const float*)d_in[2];
    const float* b1   = (const float*)d_in[3];
    const float* W2   = (const float*)d_in[4];
    const float* b2   = (const float*)d_in[5];
    const float* ffW1 = (const float*)d_in[6];
    const float* ffb1 = (const float*)d_in[7];
    const float* ffW2 = (const float*)d_in[8];
    const float* ffb2 = (const float*)d_in[9];
    const float* ffW3 = (const float*)d_in[10];
    const float* ffb3 = (const float*)d_in[11];
    const float* ffWs = (const float*)d_in[12];
    const float* ffbs = (const float*)d_in[13];
    const int* esrc = (const int*)d_in[14];
    const int* edst = (const int*)d_in[15];
    const int* gid  = (const int*)d_in[16];

    const int N = in_sizes[0] / D;
    const int E = in_sizes[1];
    float* out = (float*)d_out;

    // workspace layout (8B-aligned first)
    char* ws = (char*)d_ws;
    int2* ep = (int2*)ws;                                  // E int2 (CSR payload)
    float* A = (float*)(ep + E);                           // N*D floats
    float* pooled = A + (size_t)N * D;                     // G*D
    float* ffo = pooled + G * D;                           // G*D
    int* gcnt = (int*)(ffo + G * D);                       // G
    int* gptr = gcnt + G;                                  // G+1
    int* cnt_dst = gptr + G + 1;                           // N
    int* row_ptr = cnt_dst + N;                            // N+1
    int* cursor = row_ptr + N + 1;                         // N
    int* incl = cursor + N;                                // N
    int* bsum = incl + N;                                  // 256
    int* boff = bsum + 256;                                // 256

    float* S = out;  // reuse output buffer as SpMM result

    const dim3 blk(256);
    const int gemmGrid = (N + 31) / 32;
    const int eGrid = (E + 255) / 256;
    const int nGrid = (N + 255) / 256;
    const int nb = (N + SCAN_CHUNK - 1) / SCAN_CHUNK;

    // ---- CSR build (reused by both SpMMs)
    hipMemsetAsync(cnt_dst, 0, N * sizeof(int), stream);
    count_dst<<<eGrid, blk, 0, stream>>>(edst, cnt_dst, E);
    scan_a<<<nb, blk, 0, stream>>>(cnt_dst, incl, bsum, N);
    scan_b<<<1, 256, 0, stream>>>(bsum, boff, nb);
    scan_c<<<nGrid, blk, 0, stream>>>(cnt_dst, incl, boff, row_ptr, cursor, N);
    fill_csr<<<eGrid, blk, 0, stream>>>(esrc, edst, ew, cursor, ep, E);

    // ---- pipeline
    gemm128<false><<<gemmGrid, blk, 0, stream>>>(feat, W1, nullptr, A, N);
    spmm_csr<<<(N + 3) / 4, blk, 0, stream>>>(A, ep, row_ptr, S, N);
    gemm128<true><<<gemmGrid, blk, 0, stream>>>(S, W2, b1, A, N);
    spmm_csr<<<(N + 3) / 4, blk, 0, stream>>>(A, ep, row_ptr, S, N);

    // ---- per-graph mean pool + FF + scatter
    hipMemsetAsync(gcnt, 0, G * sizeof(int), stream);
    hist_kernel<<<nGrid, blk, 0, stream>>>(gid, gcnt, N);
    scan_kernel<<<1, G, 0, stream>>>(gcnt, gptr);
    pool_kernel<<<G, 128, 0, stream>>>(S, gptr, b2, pooled);
    ff_kernel<<<G, 128, 0, stream>>>(pooled, ffW1, ffb1, ffW2, ffb2,
                                     ffW3, ffb3, ffWs, ffbs, ffo);
    scatter_kernel<<<(int)(((size_t)N * 32 + 255) / 256), blk, 0, stream>>>(ffo, gid, out, N);
}

// Round 3
// 666.620 us; speedup vs baseline: 8.7693x; 1.3500x over previous
//
#include <hip/hip_runtime.h>
#include <math.h>

// ---------------------------------------------------------------------------
// Encoder: GCN(2 layers) + per-graph mean pool + FF MLP on pooled rows + sigmoid
// N=100000 nodes, E=1600000 edges, D=128, G=256 graphs (graph_id sorted)
// Round 3: graph_id is SORTED -> replace 256-bin atomic histogram (146us of
// same-address contention) with boundary detection. Widen pool_kernel.
// ---------------------------------------------------------------------------

#define D 128
#define G 256
#define SCAN_CHUNK 1024

// ---- Tiled fp32 GEMM: Y[nrows x 128] = transform(X) @ W (W row-major k*128+c)
template<bool BIAS_RELU>
__global__ __launch_bounds__(256, 2)
void gemm128(const float* __restrict__ X, const float* __restrict__ W,
             const float* __restrict__ bias, float* __restrict__ Y, int nrows) {
    __shared__ float Ws[64][128];
    __shared__ float Xs[32][129];
    const int tid = threadIdx.x;
    const int r0 = blockIdx.x * 32;

    for (int i = tid; i < 32 * 128; i += 256) {
        int r = i >> 7, k = i & 127;
        int gr = r0 + r;
        float v = (gr < nrows) ? X[(size_t)gr * D + k] : 0.f;
        if (BIAS_RELU) v = fmaxf(v + bias[k], 0.f);
        Xs[r][k] = v;
    }

    const int c0 = (tid & 63) * 2;
    const int rb = (tid >> 6) * 8;
    float2 acc[8];
#pragma unroll
    for (int i = 0; i < 8; i++) acc[i] = make_float2(0.f, 0.f);

    for (int kb = 0; kb < 128; kb += 64) {
        __syncthreads();
        for (int i = tid; i < 64 * 128; i += 256) {
            int k = i >> 7, c = i & 127;
            Ws[k][c] = W[(size_t)(kb + k) * D + c];
        }
        __syncthreads();
#pragma unroll 8
        for (int k = 0; k < 64; k++) {
            float w0 = Ws[k][c0], w1 = Ws[k][c0 + 1];
#pragma unroll
            for (int i = 0; i < 8; i++) {
                float xv = Xs[rb + i][kb + k];
                acc[i].x = fmaf(xv, w0, acc[i].x);
                acc[i].y = fmaf(xv, w1, acc[i].y);
            }
        }
    }
#pragma unroll
    for (int i = 0; i < 8; i++) {
        int gr = r0 + rb + i;
        if (gr < nrows)
            *(float2*)(Y + (size_t)gr * D + c0) = acc[i];
    }
}

// ======================= CSR build (counting sort by dst) ===================

__global__ __launch_bounds__(256)
void count_dst(const int* __restrict__ dst, int* __restrict__ cnt, int ne) {
    int e = blockIdx.x * 256 + threadIdx.x;
    if (e < ne) atomicAdd(&cnt[dst[e]], 1);
}

__global__ __launch_bounds__(256)
void scan_a(const int* __restrict__ cnt, int* __restrict__ incl,
            int* __restrict__ bsum, int n) {
    __shared__ int s[256];
    int b = blockIdx.x, t = threadIdx.x;
    int base = b * SCAN_CHUNK + t * 4;
    int v[4];
    int sum = 0;
#pragma unroll
    for (int i = 0; i < 4; i++) {
        int idx = base + i;
        v[i] = (idx < n) ? cnt[idx] : 0;
        sum += v[i];
    }
    s[t] = sum;
    __syncthreads();
    for (int off = 1; off < 256; off <<= 1) {
        int x = (t >= off) ? s[t - off] : 0;
        __syncthreads();
        s[t] += x;
        __syncthreads();
    }
    int run = s[t] - sum;
#pragma unroll
    for (int i = 0; i < 4; i++) {
        run += v[i];
        int idx = base + i;
        if (idx < n) incl[idx] = run;
    }
    if (t == 255) bsum[b] = s[255];
}

__global__ void scan_b(const int* __restrict__ bsum, int* __restrict__ boff, int nb) {
    __shared__ int s[256];
    int t = threadIdx.x;
    int v = (t < nb) ? bsum[t] : 0;
    s[t] = v;
    __syncthreads();
    for (int off = 1; off < 256; off <<= 1) {
        int x = (t >= off) ? s[t - off] : 0;
        __syncthreads();
        s[t] += x;
        __syncthreads();
    }
    boff[t] = s[t] - v;
}

__global__ __launch_bounds__(256)
void scan_c(const int* __restrict__ cnt, const int* __restrict__ incl,
            const int* __restrict__ boff, int* __restrict__ rp,
            int* __restrict__ cursor, int n) {
    int i = blockIdx.x * 256 + threadIdx.x;
    if (i >= n) return;
    int tot = incl[i] + boff[i / SCAN_CHUNK];
    rp[i + 1] = tot;
    cursor[i] = tot - cnt[i];
    if (i == 0) rp[0] = 0;
}

__global__ __launch_bounds__(256)
void fill_csr(const int* __restrict__ src, const int* __restrict__ dst,
              const float* __restrict__ ew, int* __restrict__ cursor,
              int2* __restrict__ ep, int ne) {
    int e = blockIdx.x * 256 + threadIdx.x;
    if (e >= ne) return;
    int t = dst[e];
    int pos = atomicAdd(&cursor[t], 1);
    ep[pos] = make_int2(src[e], __float_as_int(ew[e]));
}

// ---- Row-parallel gather SpMM: one wave per row, lane owns 2 dims
__global__ __launch_bounds__(256)
void spmm_csr(const float* __restrict__ X, const int2* __restrict__ ep,
              const int* __restrict__ rp, float* __restrict__ out, int nrows) {
    int row = blockIdx.x * 4 + (threadIdx.x >> 6);
    if (row >= nrows) return;
    int d0 = (threadIdx.x & 63) * 2;
    int beg = rp[row], end = rp[row + 1];
    float2 a0 = make_float2(0.f, 0.f), a1 = make_float2(0.f, 0.f);
    int j = beg;
    for (; j + 1 < end; j += 2) {
        int2 e0 = ep[j], e1 = ep[j + 1];
        float w0 = __int_as_float(e0.y), w1 = __int_as_float(e1.y);
        float2 x0 = *(const float2*)(X + (size_t)e0.x * D + d0);
        float2 x1 = *(const float2*)(X + (size_t)e1.x * D + d0);
        a0.x = fmaf(w0, x0.x, a0.x);
        a0.y = fmaf(w0, x0.y, a0.y);
        a1.x = fmaf(w1, x1.x, a1.x);
        a1.y = fmaf(w1, x1.y, a1.y);
    }
    if (j < end) {
        int2 e0 = ep[j];
        float w0 = __int_as_float(e0.y);
        float2 x0 = *(const float2*)(X + (size_t)e0.x * D + d0);
        a0.x = fmaf(w0, x0.x, a0.x);
        a0.y = fmaf(w0, x0.y, a0.y);
    }
    a0.x += a1.x;
    a0.y += a1.y;
    *(float2*)(out + (size_t)row * D + d0) = a0;
}

// ======================= graph pooling + FF =================================

// graph_id sorted -> graph range boundaries by adjacent-difference.
__global__ __launch_bounds__(256)
void bounds_kernel(const int* __restrict__ gid, int* __restrict__ ptr, int n) {
    int i = blockIdx.x * 256 + threadIdx.x;
    if (i >= n) return;
    int b = gid[i];
    int a = (i == 0) ? -1 : gid[i - 1];
    for (int g = a + 1; g <= b; g++) ptr[g] = i;   // first node of graph g
    if (i == n - 1) {
        for (int g = b + 1; g <= G; g++) ptr[g] = n;
    }
}

// mean pool over contiguous row range; 512 threads = 4 row-groups x 128 dims
__global__ __launch_bounds__(512)
void pool_kernel(const float* __restrict__ S, const int* __restrict__ ptr,
                 const float* __restrict__ b2, float* __restrict__ pooled) {
    __shared__ float red[4][128];
    int g = blockIdx.x;
    int d = threadIdx.x & 127;
    int r = threadIdx.x >> 7;
    int beg = ptr[g], end = ptr[g + 1];
    float acc = 0.f;
    for (int n = beg + r; n < end; n += 4) acc += S[(size_t)n * D + d];
    red[r][d] = acc;
    __syncthreads();
    if (r == 0) {
        float s = red[0][d] + red[1][d] + red[2][d] + red[3][d];
        int cnt = end - beg;
        pooled[g * D + d] = (cnt > 0) ? (s / (float)cnt + b2[d]) : 0.f;
    }
}

__global__ __launch_bounds__(128)
void ff_kernel(const float* __restrict__ pooled,
               const float* __restrict__ W1, const float* __restrict__ b1,
               const float* __restrict__ W2, const float* __restrict__ b2,
               const float* __restrict__ W3, const float* __restrict__ b3,
               const float* __restrict__ Wsc, const float* __restrict__ bsc,
               float* __restrict__ ffout) {
    __shared__ float hx[D], za[D], zb[D];
    int g = blockIdx.x, d = threadIdx.x;
    hx[d] = pooled[g * D + d];
    __syncthreads();
    float s = b1[d];
    for (int k = 0; k < D; k++) s = fmaf(hx[k], W1[k * D + d], s);
    za[d] = fmaxf(s, 0.f);
    __syncthreads();
    s = b2[d];
    for (int k = 0; k < D; k++) s = fmaf(za[k], W2[k * D + d], s);
    zb[d] = fmaxf(s, 0.f);
    __syncthreads();
    s = b3[d];
    for (int k = 0; k < D; k++) s = fmaf(zb[k], W3[k * D + d], s);
    float z3 = fmaxf(s, 0.f);
    float sc = bsc[d];
    for (int k = 0; k < D; k++) sc = fmaf(hx[k], Wsc[k * D + d], sc);
    float v = z3 + sc;
    ffout[g * D + d] = 1.f / (1.f + expf(-v));
}

__global__ __launch_bounds__(256)
void scatter_kernel(const float* __restrict__ ffout, const int* __restrict__ gid,
                    float* __restrict__ out, int n) {
    unsigned idx = blockIdx.x * 256u + threadIdx.x;
    unsigned node = idx >> 5;
    if (node >= (unsigned)n) return;
    int d0 = (idx & 31) * 4;
    int g = gid[node];
    *(float4*)(out + (size_t)node * D + d0) = *(const float4*)(ffout + g * D + d0);
}

extern "C" void kernel_launch(void* const* d_in, const int* in_sizes, int n_in,
                              void* d_out, int out_size, void* d_ws, size_t ws_size,
                              hipStream_t stream) {
    const float* feat = (const float*)d_in[0];
    const float* ew   = (const float*)d_in[1];
    const float* W1   = (const float*)d_in[2];
    const float* b1   = (const float*)d_in[3];
    const float* W2   = (const float*)d_in[4];
    const float* b2   = (const float*)d_in[5];
    const float* ffW1 = (const float*)d_in[6];
    const float* ffb1 = (const float*)d_in[7];
    const float* ffW2 = (const float*)d_in[8];
    const float* ffb2 = (const float*)d_in[9];
    const float* ffW3 = (const float*)d_in[10];
    const float* ffb3 = (const float*)d_in[11];
    const float* ffWs = (const float*)d_in[12];
    const float* ffbs = (const float*)d_in[13];
    const int* esrc = (const int*)d_in[14];
    const int* edst = (const int*)d_in[15];
    const int* gid  = (const int*)d_in[16];

    const int N = in_sizes[0] / D;
    const int E = in_sizes[1];
    float* out = (float*)d_out;

    // workspace layout (8B-aligned first)
    char* ws = (char*)d_ws;
    int2* ep = (int2*)ws;                                  // E int2 (CSR payload)
    float* A = (float*)(ep + E);                           // N*D floats
    float* pooled = A + (size_t)N * D;                     // G*D
    float* ffo = pooled + G * D;                           // G*D
    int* gptr = (int*)(ffo + G * D);                       // G+1
    int* cnt_dst = gptr + G + 1;                           // N
    int* row_ptr = cnt_dst + N;                            // N+1
    int* cursor = row_ptr + N + 1;                         // N
    int* incl = cursor + N;                                // N
    int* bsum = incl + N;                                  // 256
    int* boff = bsum + 256;                                // 256

    float* S = out;  // reuse output buffer as SpMM result

    const dim3 blk(256);
    const int gemmGrid = (N + 31) / 32;
    const int eGrid = (E + 255) / 256;
    const int nGrid = (N + 255) / 256;
    const int nb = (N + SCAN_CHUNK - 1) / SCAN_CHUNK;

    // ---- CSR build (reused by both SpMMs)
    hipMemsetAsync(cnt_dst, 0, N * sizeof(int), stream);
    count_dst<<<eGrid, blk, 0, stream>>>(edst, cnt_dst, E);
    scan_a<<<nb, blk, 0, stream>>>(cnt_dst, incl, bsum, N);
    scan_b<<<1, 256, 0, stream>>>(bsum, boff, nb);
    scan_c<<<nGrid, blk, 0, stream>>>(cnt_dst, incl, boff, row_ptr, cursor, N);
    fill_csr<<<eGrid, blk, 0, stream>>>(esrc, edst, ew, cursor, ep, E);

    // ---- graph boundaries from sorted gid (no atomics)
    bounds_kernel<<<nGrid, blk, 0, stream>>>(gid, gptr, N);

    // ---- pipeline
    gemm128<false><<<gemmGrid, blk, 0, stream>>>(feat, W1, nullptr, A, N);
    spmm_csr<<<(N + 3) / 4, blk, 0, stream>>>(A, ep, row_ptr, S, N);
    gemm128<true><<<gemmGrid, blk, 0, stream>>>(S, W2, b1, A, N);
    spmm_csr<<<(N + 3) / 4, blk, 0, stream>>>(A, ep, row_ptr, S, N);

    // ---- per-graph mean pool + FF + scatter
    pool_kernel<<<G, 512, 0, stream>>>(S, gptr, b2, pooled);
    ff_kernel<<<G, 128, 0, stream>>>(pooled, ffW1, ffb1, ffW2, ffb2,
                                     ffW3, ffb3, ffWs, ffbs, ffo);
    scatter_kernel<<<(int)(((size_t)N * 32 + 255) / 256), blk, 0, stream>>>(ffo, gid, out, N);
}